// Round 1
// baseline (6194.749 us; speedup 1.0000x reference)
//
#include <hip/hip_runtime.h>

typedef _Float16 half_t;
typedef _Float16 half8 __attribute__((ext_vector_type(8)));
typedef float floatx4 __attribute__((ext_vector_type(4)));

#define SEQ 256
#define BATCH 64
#define EMB 256
#define HID 512
#define NOUT 18
#define M_TOT (SEQ*BATCH)   // 16384

// ---------------- ws layout (bytes) ----------------
#define O_CNT    0u          // 4 groups of counters, 64B apart (256B)
#define O_HB0    256u        // layer0 h double buffers: [2 dir][2][64][512] half = 262144
#define O_HB1    262400u     // layer1 same
#define O_EMFC16 524544u     // 65536 half
#define O_WIH0   655616u     // 1024*256 half
#define O_WIH1   1179904u    // 1024*1024 half
#define O_FC16   3277056u    // 18*1024 half
#define O_PE     3313920u    // post_emb 16384*256 half
#define O_XP     11702528u   // xp 16384*1024 half (shared by layer0/layer1)
#define O_OUT0   45256960u   // 16384*1024 half
#define O_OUT1   78811392u   // 16384*1024 half
// total 112365824 bytes

// ---------------- init: zero counters + h buffers ----------------
__global__ void zero_ws(uint4* p, int n) {
    int i = blockIdx.x * 256 + threadIdx.x;
    if (i < n) p[i] = make_uint4(0u, 0u, 0u, 0u);
}

// ---------------- fp32 -> fp16 convert (8 elems/thread) ----------------
__global__ void cvt_f32f16(const float* __restrict__ s, half_t* __restrict__ d, int n8) {
    int i = blockIdx.x * 256 + threadIdx.x;
    if (i < n8) {
        const float4* s4 = (const float4*)s;
        float4 a = s4[2*i], b = s4[2*i+1];
        half8 h;
        h[0]=(_Float16)a.x; h[1]=(_Float16)a.y; h[2]=(_Float16)a.z; h[3]=(_Float16)a.w;
        h[4]=(_Float16)b.x; h[5]=(_Float16)b.y; h[6]=(_Float16)b.z; h[7]=(_Float16)b.w;
        *(half8*)(d + (size_t)i*8) = h;
    }
}

// ---------------- generic NT GEMM: C[m,n] = sum_k A[m,k]*B[n,k] + bias ----------------
// BM=128 BN=128 BK=32, 256 threads (4 waves 2x2), fp16 MFMA 16x16x32, fp16 out.
// GATHER mode: A row r is emb_table[text[m0+r]] (fp32 -> fp16 on stage).
// LDS chunk swizzle: logical k-chunk c of row r stored at phase (c+(r>>1))&3  -> 2-way conflicts (free).
template<bool GATHER>
__global__ __launch_bounds__(256)
void gemm_nt(const half_t* __restrict__ A, const float* __restrict__ Atab,
             const int* __restrict__ gidx, const half_t* __restrict__ Bm,
             const float* __restrict__ bias0, const float* __restrict__ bias1,
             half_t* __restrict__ Cout, int M, int N, int K)
{
    __shared__ half8 As8[512];   // 128 x 32 half
    __shared__ half8 Bs8[512];
    half_t* As = (half_t*)As8;
    half_t* Bs = (half_t*)Bs8;

    const int tid  = threadIdx.x;
    const int lane = tid & 63, wid = tid >> 6;
    const int wm = wid >> 1, wn = wid & 1;
    const int ln = lane & 15, hi = lane >> 4;
    const int m0 = blockIdx.x * 128, n0 = blockIdx.y * 128;

    floatx4 acc[4][4] = {};
    const int kTiles = K >> 5;

    for (int kt = 0; kt < kTiles; ++kt) {
        if constexpr (GATHER) {
            int r = tid >> 1, q = tid & 1;
            int row = gidx[m0 + r];
            const float* src = Atab + (size_t)row * EMB + kt*32 + q*16;
            float4 f0 = *(const float4*)(src);
            float4 f1 = *(const float4*)(src + 4);
            float4 f2 = *(const float4*)(src + 8);
            float4 f3 = *(const float4*)(src + 12);
            half8 h0, h1;
            h0[0]=(_Float16)f0.x; h0[1]=(_Float16)f0.y; h0[2]=(_Float16)f0.z; h0[3]=(_Float16)f0.w;
            h0[4]=(_Float16)f1.x; h0[5]=(_Float16)f1.y; h0[6]=(_Float16)f1.z; h0[7]=(_Float16)f1.w;
            h1[0]=(_Float16)f2.x; h1[1]=(_Float16)f2.y; h1[2]=(_Float16)f2.z; h1[3]=(_Float16)f2.w;
            h1[4]=(_Float16)f3.x; h1[5]=(_Float16)f3.y; h1[6]=(_Float16)f3.z; h1[7]=(_Float16)f3.w;
            int c0 = 2*q, c1 = 2*q + 1;
            *(half8*)(As + r*32 + (((c0 + (r>>1)) & 3) * 8)) = h0;
            *(half8*)(As + r*32 + (((c1 + (r>>1)) & 3) * 8)) = h1;
        } else {
            #pragma unroll
            for (int ii = 0; ii < 2; ++ii) {
                int ch = tid + ii*256; int r = ch >> 2, c = ch & 3;
                half8 v = *(const half8*)(A + (size_t)(m0+r)*K + kt*32 + c*8);
                *(half8*)(As + r*32 + (((c + (r>>1)) & 3) * 8)) = v;
            }
        }
        #pragma unroll
        for (int ii = 0; ii < 2; ++ii) {
            int ch = tid + ii*256; int r = ch >> 2, c = ch & 3;
            half8 v = *(const half8*)(Bm + (size_t)(n0+r)*K + kt*32 + c*8);
            *(half8*)(Bs + r*32 + (((c + (r>>1)) & 3) * 8)) = v;
        }
        __syncthreads();

        half8 af[4], bf[4];
        #pragma unroll
        for (int mt = 0; mt < 4; ++mt) {
            int r = wm*64 + mt*16 + ln;
            af[mt] = *(const half8*)(As + r*32 + ((hi + (r>>1)) & 3) * 8);
        }
        #pragma unroll
        for (int nt = 0; nt < 4; ++nt) {
            int r = wn*64 + nt*16 + ln;
            bf[nt] = *(const half8*)(Bs + r*32 + ((hi + (r>>1)) & 3) * 8);
        }
        #pragma unroll
        for (int mt = 0; mt < 4; ++mt)
            #pragma unroll
            for (int nt = 0; nt < 4; ++nt)
                acc[mt][nt] = __builtin_amdgcn_mfma_f32_16x16x32_f16(af[mt], bf[nt], acc[mt][nt], 0, 0, 0);
        __syncthreads();
    }

    #pragma unroll
    for (int mt = 0; mt < 4; ++mt) {
        #pragma unroll
        for (int nt = 0; nt < 4; ++nt) {
            int n = n0 + wn*64 + nt*16 + ln;
            float bv = (bias0 ? bias0[n] : 0.f) + (bias1 ? bias1[n] : 0.f);
            #pragma unroll
            for (int r = 0; r < 4; ++r) {
                int m = m0 + wm*64 + mt*16 + hi*4 + r;
                Cout[(size_t)m*N + n] = (half_t)(acc[mt][nt][r] + bv);
            }
        }
    }
}

// ---------------- persistent bidirectional RNN layer ----------------
// grid = 32 blocks x 256 thr. dir = bid>>4 (0 fwd, 1 bwd); j-slice = (bid&15)*32.
// wave w handles batch rows [16w,16w+16), j in [j0,j0+32): W slice kept in registers
// as pre-packed B fragments. h broadcast via global double buffer + atomic barrier.
__global__ __launch_bounds__(256, 1)
void rnn_layer(const half_t* __restrict__ xp, half_t* __restrict__ outbuf,
               const float* __restrict__ whh, half_t* __restrict__ hb,
               int* __restrict__ cnt)
{
    const int bid = blockIdx.x;
    const int dir = bid >> 4;
    const int j0  = (bid & 15) * 32;
    const int wid = threadIdx.x >> 6, lane = threadIdx.x & 63;
    const int ln = lane & 15, hi = lane >> 4;
    const int b0 = wid * 16;

    // load + pack W fragments: bfrag[nt][kk] lane holds W[j0+nt*16+ln][kk*32+hi*8 + i]
    half8 bfrag[2][16];
    #pragma unroll
    for (int nt = 0; nt < 2; ++nt) {
        #pragma unroll
        for (int kk = 0; kk < 16; ++kk) {
            const float* wp = whh + ((size_t)(dir*HID + j0 + nt*16 + ln))*HID + kk*32 + hi*8;
            float4 f0 = *(const float4*)wp;
            float4 f1 = *(const float4*)(wp + 4);
            half8 h;
            h[0]=(_Float16)f0.x; h[1]=(_Float16)f0.y; h[2]=(_Float16)f0.z; h[3]=(_Float16)f0.w;
            h[4]=(_Float16)f1.x; h[5]=(_Float16)f1.y; h[6]=(_Float16)f1.z; h[7]=(_Float16)f1.w;
            bfrag[nt][kk] = h;
        }
    }

    half_t* hb_d = hb + (size_t)dir * (2*BATCH*HID);
    int* cp = cnt + dir*16;   // 64B apart
    int tgt = 0;

    for (int step = 0; step < SEQ; ++step) {
        const int t = dir ? (SEQ-1 - step) : step;
        const half_t* hc = hb_d + (size_t)(step & 1) * (BATCH*HID);
        half_t* hn       = hb_d + (size_t)((step+1) & 1) * (BATCH*HID);

        half8 af[16];
        #pragma unroll
        for (int kk = 0; kk < 16; ++kk)
            af[kk] = *(const half8*)(hc + (size_t)(b0+ln)*HID + kk*32 + hi*8);

        floatx4 acc0 = {0.f,0.f,0.f,0.f};
        floatx4 acc1 = {0.f,0.f,0.f,0.f};
        #pragma unroll
        for (int kk = 0; kk < 16; ++kk) {
            acc0 = __builtin_amdgcn_mfma_f32_16x16x32_f16(af[kk], bfrag[0][kk], acc0, 0, 0, 0);
            acc1 = __builtin_amdgcn_mfma_f32_16x16x32_f16(af[kk], bfrag[1][kk], acc1, 0, 0, 0);
        }

        const size_t mrow = (size_t)t * BATCH;
        #pragma unroll
        for (int nt = 0; nt < 2; ++nt) {
            floatx4 a = nt ? acc1 : acc0;
            #pragma unroll
            for (int r = 0; r < 4; ++r) {
                int b = b0 + hi*4 + r;
                int j = j0 + nt*16 + ln;
                float v = a[r] + (float)xp[(mrow + b)*(2*HID) + dir*HID + j];
                v = fmaxf(v, 0.f);
                half_t hv = (half_t)v;
                hn[(size_t)b*HID + j] = hv;
                outbuf[(mrow + b)*(2*HID) + dir*HID + j] = hv;
            }
        }

        // barrier: 64 waves per direction, monotonic counter
        tgt += 64;
        if (lane == 0)
            __hip_atomic_fetch_add(cp, 1, __ATOMIC_RELEASE, __HIP_MEMORY_SCOPE_AGENT);
        while (__hip_atomic_load(cp, __ATOMIC_ACQUIRE, __HIP_MEMORY_SCOPE_AGENT) < tgt)
            __builtin_amdgcn_s_sleep(1);
    }
}

// ---------------- final FC: [16384,1024] x [18,1024]^T + b ----------------
__global__ __launch_bounds__(256)
void fc_kernel(const half_t* __restrict__ X, const half_t* __restrict__ W16,
               const float* __restrict__ bias, float* __restrict__ Y)
{
    __shared__ half8 Ws8[2304];   // 18*1024 half
    half_t* Ws = (half_t*)Ws8;
    for (int ch = threadIdx.x; ch < 2304; ch += 256)
        Ws8[ch] = *(const half8*)(W16 + (size_t)ch*8);
    __syncthreads();

    int wi = threadIdx.x >> 6, lane = threadIdx.x & 63;
    int m = blockIdx.x*4 + wi;
    const half_t* xr = X + (size_t)m*1024 + lane*16;
    half8 x0 = *(const half8*)xr;
    half8 x1 = *(const half8*)(xr + 8);
    float xa[16];
    #pragma unroll
    for (int i = 0; i < 8; ++i) { xa[i] = (float)x0[i]; xa[8+i] = (float)x1[i]; }

    for (int n = 0; n < NOUT; ++n) {
        const half_t* wr = Ws + n*1024 + lane*16;
        half8 w0 = *(const half8*)wr;
        half8 w1 = *(const half8*)(wr + 8);
        float s = 0.f;
        #pragma unroll
        for (int i = 0; i < 8; ++i) s += xa[i]*(float)w0[i] + xa[8+i]*(float)w1[i];
        #pragma unroll
        for (int off = 32; off > 0; off >>= 1) s += __shfl_down(s, off, 64);
        if (lane == 0) Y[(size_t)m*NOUT + n] = s + bias[n];
    }
}

// ---------------- launcher ----------------
extern "C" void kernel_launch(void* const* d_in, const int* in_sizes, int n_in,
                              void* d_out, int out_size, void* d_ws, size_t ws_size,
                              hipStream_t stream)
{
    const int*   text    = (const int*)  d_in[0];
    const float* emb     = (const float*)d_in[1];
    const float* emfc_w  = (const float*)d_in[2];
    const float* emfc_b  = (const float*)d_in[3];
    const float* w_ih0   = (const float*)d_in[4];
    const float* w_hh0   = (const float*)d_in[5];
    const float* b_ih0   = (const float*)d_in[6];
    const float* b_hh0   = (const float*)d_in[7];
    const float* w_ih1   = (const float*)d_in[8];
    const float* w_hh1   = (const float*)d_in[9];
    const float* b_ih1   = (const float*)d_in[10];
    const float* b_hh1   = (const float*)d_in[11];
    const float* fc_w    = (const float*)d_in[12];
    const float* fc_b    = (const float*)d_in[13];
    float* out = (float*)d_out;

    char* ws = (char*)d_ws;
    int*    cnt    = (int*)   (ws + O_CNT);
    half_t* hb0    = (half_t*)(ws + O_HB0);
    half_t* hb1    = (half_t*)(ws + O_HB1);
    half_t* emfc16 = (half_t*)(ws + O_EMFC16);
    half_t* wih0   = (half_t*)(ws + O_WIH0);
    half_t* wih1   = (half_t*)(ws + O_WIH1);
    half_t* fc16   = (half_t*)(ws + O_FC16);
    half_t* pe     = (half_t*)(ws + O_PE);
    half_t* xp     = (half_t*)(ws + O_XP);
    half_t* out0   = (half_t*)(ws + O_OUT0);
    half_t* out1   = (half_t*)(ws + O_OUT1);

    // 1) zero counters + h buffers  (524544 bytes = 32784 uint4)
    zero_ws<<<129, 256, 0, stream>>>((uint4*)ws, 32784);

    // 2) weight conversions fp32->fp16
    cvt_f32f16<<<32,  256, 0, stream>>>(emfc_w, emfc16, 8192);
    cvt_f32f16<<<128, 256, 0, stream>>>(w_ih0,  wih0,  32768);
    cvt_f32f16<<<512, 256, 0, stream>>>(w_ih1,  wih1, 131072);
    cvt_f32f16<<<9,   256, 0, stream>>>(fc_w,   fc16,   2304);

    // 3) post_emb = gather(emb, text) @ emfc_w^T + emfc_b
    gemm_nt<true><<<dim3(M_TOT/128, EMB/128), 256, 0, stream>>>(
        nullptr, emb, text, emfc16, emfc_b, nullptr, pe, M_TOT, EMB, EMB);

    // 4) xp0 = post_emb @ w_ih0^T + (b_ih0 + b_hh0)   [N = 2*512 dirs concat]
    gemm_nt<false><<<dim3(M_TOT/128, (2*HID)/128), 256, 0, stream>>>(
        pe, nullptr, nullptr, wih0, b_ih0, b_hh0, xp, M_TOT, 2*HID, EMB);

    // 5) layer0 recurrence (both directions)
    rnn_layer<<<32, 256, 0, stream>>>(xp, out0, w_hh0, hb0, cnt);

    // 6) xp1 = out0 @ w_ih1^T + (b_ih1 + b_hh1)
    gemm_nt<false><<<dim3(M_TOT/128, (2*HID)/128), 256, 0, stream>>>(
        out0, nullptr, nullptr, wih1, b_ih1, b_hh1, xp, M_TOT, 2*HID, 2*HID);

    // 7) layer1 recurrence
    rnn_layer<<<32, 256, 0, stream>>>(xp, out1, w_hh1, hb1, cnt + 32);

    // 8) out = out1 @ fc_w^T + fc_b
    fc_kernel<<<M_TOT/4, 256, 0, stream>>>(out1, fc16, fc_b, out);
}

// Round 2
// 3199.461 us; speedup vs baseline: 1.9362x; 1.9362x over previous
//
#include <hip/hip_runtime.h>

typedef _Float16 half_t;
typedef _Float16 half4 __attribute__((ext_vector_type(4)));
typedef _Float16 half8 __attribute__((ext_vector_type(8)));
typedef float floatx4 __attribute__((ext_vector_type(4)));
typedef unsigned long long ull_t;

#define SEQ 256
#define BATCH 64
#define EMB 256
#define HID 512
#define NOUT 18
#define M_TOT (SEQ*BATCH)   // 16384

// ---------------- ws layout (bytes) ----------------
#define O_CNT    0u          // 4 counters, 64B apart (256B)
#define O_HB0    256u        // layer0 h double buffers: [2 dir][2][64][512] half = 262144
#define O_HB1    262400u     // layer1 same
#define O_EMFC16 524544u     // 65536 half
#define O_WIH0   655616u     // 1024*256 half
#define O_WIH1   1179904u    // 1024*1024 half
#define O_FC16   3277056u    // 18*1024 half
#define O_PE     3313920u    // post_emb 16384*256 half
#define O_XP     11702528u   // xp 16384*1024 half (shared by layer0/layer1)
#define O_OUT0   45256960u   // 16384*1024 half
#define O_OUT1   78811392u   // 16384*1024 half
// total 112365824 bytes

// ---------------- init: zero counters + h buffers ----------------
__global__ void zero_ws(uint4* p, int n) {
    int i = blockIdx.x * 256 + threadIdx.x;
    if (i < n) p[i] = make_uint4(0u, 0u, 0u, 0u);
}

// ---------------- fp32 -> fp16 convert (8 elems/thread) ----------------
__global__ void cvt_f32f16(const float* __restrict__ s, half_t* __restrict__ d, int n8) {
    int i = blockIdx.x * 256 + threadIdx.x;
    if (i < n8) {
        const float4* s4 = (const float4*)s;
        float4 a = s4[2*i], b = s4[2*i+1];
        half8 h;
        h[0]=(_Float16)a.x; h[1]=(_Float16)a.y; h[2]=(_Float16)a.z; h[3]=(_Float16)a.w;
        h[4]=(_Float16)b.x; h[5]=(_Float16)b.y; h[6]=(_Float16)b.z; h[7]=(_Float16)b.w;
        *(half8*)(d + (size_t)i*8) = h;
    }
}

// ---------------- generic NT GEMM: C[m,n] = sum_k A[m,k]*B[n,k] + bias ----------------
// BM=128 BN=128 BK=32, 256 threads (4 waves 2x2), fp16 MFMA 16x16x32, fp16 out.
template<bool GATHER>
__global__ __launch_bounds__(256)
void gemm_nt(const half_t* __restrict__ A, const float* __restrict__ Atab,
             const int* __restrict__ gidx, const half_t* __restrict__ Bm,
             const float* __restrict__ bias0, const float* __restrict__ bias1,
             half_t* __restrict__ Cout, int M, int N, int K)
{
    __shared__ half8 As8[512];   // 128 x 32 half
    __shared__ half8 Bs8[512];
    half_t* As = (half_t*)As8;
    half_t* Bs = (half_t*)Bs8;

    const int tid  = threadIdx.x;
    const int lane = tid & 63, wid = tid >> 6;
    const int wm = wid >> 1, wn = wid & 1;
    const int ln = lane & 15, hi = lane >> 4;
    const int m0 = blockIdx.x * 128, n0 = blockIdx.y * 128;

    floatx4 acc[4][4] = {};
    const int kTiles = K >> 5;

    for (int kt = 0; kt < kTiles; ++kt) {
        if constexpr (GATHER) {
            int r = tid >> 1, q = tid & 1;
            int row = gidx[m0 + r];
            const float* src = Atab + (size_t)row * EMB + kt*32 + q*16;
            float4 f0 = *(const float4*)(src);
            float4 f1 = *(const float4*)(src + 4);
            float4 f2 = *(const float4*)(src + 8);
            float4 f3 = *(const float4*)(src + 12);
            half8 h0, h1;
            h0[0]=(_Float16)f0.x; h0[1]=(_Float16)f0.y; h0[2]=(_Float16)f0.z; h0[3]=(_Float16)f0.w;
            h0[4]=(_Float16)f1.x; h0[5]=(_Float16)f1.y; h0[6]=(_Float16)f1.z; h0[7]=(_Float16)f1.w;
            h1[0]=(_Float16)f2.x; h1[1]=(_Float16)f2.y; h1[2]=(_Float16)f2.z; h1[3]=(_Float16)f2.w;
            h1[4]=(_Float16)f3.x; h1[5]=(_Float16)f3.y; h1[6]=(_Float16)f3.z; h1[7]=(_Float16)f3.w;
            int c0 = 2*q, c1 = 2*q + 1;
            *(half8*)(As + r*32 + (((c0 + (r>>1)) & 3) * 8)) = h0;
            *(half8*)(As + r*32 + (((c1 + (r>>1)) & 3) * 8)) = h1;
        } else {
            #pragma unroll
            for (int ii = 0; ii < 2; ++ii) {
                int ch = tid + ii*256; int r = ch >> 2, c = ch & 3;
                half8 v = *(const half8*)(A + (size_t)(m0+r)*K + kt*32 + c*8);
                *(half8*)(As + r*32 + (((c + (r>>1)) & 3) * 8)) = v;
            }
        }
        #pragma unroll
        for (int ii = 0; ii < 2; ++ii) {
            int ch = tid + ii*256; int r = ch >> 2, c = ch & 3;
            half8 v = *(const half8*)(Bm + (size_t)(n0+r)*K + kt*32 + c*8);
            *(half8*)(Bs + r*32 + (((c + (r>>1)) & 3) * 8)) = v;
        }
        __syncthreads();

        half8 af[4], bf[4];
        #pragma unroll
        for (int mt = 0; mt < 4; ++mt) {
            int r = wm*64 + mt*16 + ln;
            af[mt] = *(const half8*)(As + r*32 + ((hi + (r>>1)) & 3) * 8);
        }
        #pragma unroll
        for (int nt = 0; nt < 4; ++nt) {
            int r = wn*64 + nt*16 + ln;
            bf[nt] = *(const half8*)(Bs + r*32 + ((hi + (r>>1)) & 3) * 8);
        }
        #pragma unroll
        for (int mt = 0; mt < 4; ++mt)
            #pragma unroll
            for (int nt = 0; nt < 4; ++nt)
                acc[mt][nt] = __builtin_amdgcn_mfma_f32_16x16x32_f16(af[mt], bf[nt], acc[mt][nt], 0, 0, 0);
        __syncthreads();
    }

    #pragma unroll
    for (int mt = 0; mt < 4; ++mt) {
        #pragma unroll
        for (int nt = 0; nt < 4; ++nt) {
            int n = n0 + wn*64 + nt*16 + ln;
            float bv = (bias0 ? bias0[n] : 0.f) + (bias1 ? bias1[n] : 0.f);
            #pragma unroll
            for (int r = 0; r < 4; ++r) {
                int m = m0 + wm*64 + mt*16 + hi*4 + r;
                Cout[(size_t)m*N + n] = (half_t)(acc[mt][nt][r] + bv);
            }
        }
    }
}

// ---------------- persistent bidirectional RNN layer (round 2) ----------------
// grid = 32 blocks x 256 thr. dir = bid>>4; j-slice = (bid&15)*32; wave w -> batches [16w,16w+16).
// D[j][b] = sum_k W[j][k] h[b][k]: A = W (registers), B = h (contiguous 16B/lane loads).
// C/D layout gives each lane 4 consecutive j for one b -> single 8B atomic store, no shuffles.
// h exchanged via RELAXED agent-scope atomics (L3 point coherence, no wbl2/inv).
// Barrier: __syncthreads (drains vmcnt) -> 1 relaxed fetch_add per block -> lane-0 relaxed poll.
__global__ __launch_bounds__(256, 1)
void rnn_layer(const half_t* __restrict__ xp, half_t* __restrict__ outbuf,
               const float* __restrict__ whh, ull_t* __restrict__ hb,
               int* __restrict__ cnt)
{
    const int bid = blockIdx.x;
    const int dir = bid >> 4;
    const int j0  = (bid & 15) * 32;
    const int wid = threadIdx.x >> 6, lane = threadIdx.x & 63;
    const int ln = lane & 15, hi = lane >> 4;
    const int b0 = wid * 16;

    // A-operand (W) fragments: afrag[mt][kk] lane holds W[j0+mt*16+ln][kk*32+hi*8 + i]
    half8 afrag[2][16];
    #pragma unroll
    for (int mt = 0; mt < 2; ++mt) {
        #pragma unroll
        for (int kk = 0; kk < 16; ++kk) {
            const float* wp = whh + ((size_t)(dir*HID + j0 + mt*16 + ln))*HID + kk*32 + hi*8;
            float4 f0 = *(const float4*)wp;
            float4 f1 = *(const float4*)(wp + 4);
            half8 h;
            h[0]=(_Float16)f0.x; h[1]=(_Float16)f0.y; h[2]=(_Float16)f0.z; h[3]=(_Float16)f0.w;
            h[4]=(_Float16)f1.x; h[5]=(_Float16)f1.y; h[6]=(_Float16)f1.z; h[7]=(_Float16)f1.w;
            afrag[mt][kk] = h;
        }
    }

    // h double buffers in ull units: [2 buf][8192 ull] per direction
    ull_t* hb_d = hb + (size_t)dir * 16384;
    int* cp = cnt + dir*16;   // 64B apart per direction

    // per-lane fixed offsets
    const int b    = b0 + ln;                       // batch row this lane reads/writes
    const int jb0  = j0 + hi*4;                     // j quad base, mt adds 16
    const int hrd  = b*128 + hi*2;                  // ull idx base for B-frag reads (+kk*8)
    const int hwr  = b*128 + (jb0 >> 2);            // ull idx base for h writes (+mt*4)

    // prefetch xp for step 0
    half4 xq[2];
    {
        int t0 = dir ? (SEQ-1) : 0;
        const half_t* xb = xp + ((size_t)(t0*BATCH + b))*(2*HID) + dir*HID + jb0;
        xq[0] = *(const half4*)(xb);
        xq[1] = *(const half4*)(xb + 16);
    }

    int tgt = 0;
    for (int step = 0; step < SEQ; ++step) {
        const int t = dir ? (SEQ-1 - step) : step;
        const ull_t* hc = hb_d + (size_t)(step & 1) * 8192;
        ull_t*       hn = hb_d + (size_t)((step+1) & 1) * 8192;

        // wait until h_step fully published (16 block-posts per prior step)
        if (step) {
            if (lane == 0)
                while (__hip_atomic_load(cp, __ATOMIC_RELAXED, __HIP_MEMORY_SCOPE_AGENT) < tgt)
                    __builtin_amdgcn_s_sleep(1);
        }

        // B-operand (h) fragments: 2 relaxed 8B atomic loads per kk (16B contiguous)
        half8 bf[16];
        #pragma unroll
        for (int kk = 0; kk < 16; ++kk) {
            const ull_t* p = hc + hrd + kk*8;
            struct U2 { ull_t a, c; } u;
            u.a = __hip_atomic_load(p,     __ATOMIC_RELAXED, __HIP_MEMORY_SCOPE_AGENT);
            u.c = __hip_atomic_load(p + 1, __ATOMIC_RELAXED, __HIP_MEMORY_SCOPE_AGENT);
            bf[kk] = __builtin_bit_cast(half8, u);
        }

        floatx4 acc0 = {0.f,0.f,0.f,0.f};
        floatx4 acc1 = {0.f,0.f,0.f,0.f};
        #pragma unroll
        for (int kk = 0; kk < 16; ++kk) {
            acc0 = __builtin_amdgcn_mfma_f32_16x16x32_f16(afrag[0][kk], bf[kk], acc0, 0, 0, 0);
            acc1 = __builtin_amdgcn_mfma_f32_16x16x32_f16(afrag[1][kk], bf[kk], acc1, 0, 0, 0);
        }

        // epilogue: v = relu(acc + xp); lane holds j quad {jb0+mt*16 .. +4} for batch b
        const size_t orow = ((size_t)t*BATCH + b)*(2*HID) + dir*HID;
        #pragma unroll
        for (int mt = 0; mt < 2; ++mt) {
            floatx4 a = mt ? acc1 : acc0;
            half4 hv;
            #pragma unroll
            for (int r = 0; r < 4; ++r)
                hv[r] = (_Float16)fmaxf(a[r] + (float)xq[mt][r], 0.f);
            *(half4*)(outbuf + orow + jb0 + mt*16) = hv;            // normal cached store
            __hip_atomic_store(hn + hwr + mt*4,
                               __builtin_bit_cast(ull_t, hv),
                               __ATOMIC_RELAXED, __HIP_MEMORY_SCOPE_AGENT);
        }

        if (step + 1 < SEQ) {
            __builtin_amdgcn_s_waitcnt(0);     // h stores acked at coherence point
            __syncthreads();                   // all 4 waves of block done
            if (threadIdx.x == 0)
                __hip_atomic_fetch_add(cp, 1, __ATOMIC_RELAXED, __HIP_MEMORY_SCOPE_AGENT);
            tgt += 16;
            // prefetch xp for next step (off critical path)
            int tn = dir ? (SEQ-2 - step) : (step+1);
            const half_t* xb = xp + ((size_t)(tn*BATCH + b))*(2*HID) + dir*HID + jb0;
            xq[0] = *(const half4*)(xb);
            xq[1] = *(const half4*)(xb + 16);
        }
    }
}

// ---------------- final FC: [16384,1024] x [18,1024]^T + b ----------------
__global__ __launch_bounds__(256)
void fc_kernel(const half_t* __restrict__ X, const half_t* __restrict__ W16,
               const float* __restrict__ bias, float* __restrict__ Y)
{
    __shared__ half8 Ws8[2304];   // 18*1024 half
    half_t* Ws = (half_t*)Ws8;
    for (int ch = threadIdx.x; ch < 2304; ch += 256)
        Ws8[ch] = *(const half8*)(W16 + (size_t)ch*8);
    __syncthreads();

    int wi = threadIdx.x >> 6, lane = threadIdx.x & 63;
    int m = blockIdx.x*4 + wi;
    const half_t* xr = X + (size_t)m*1024 + lane*16;
    half8 x0 = *(const half8*)xr;
    half8 x1 = *(const half8*)(xr + 8);
    float xa[16];
    #pragma unroll
    for (int i = 0; i < 8; ++i) { xa[i] = (float)x0[i]; xa[8+i] = (float)x1[i]; }

    for (int n = 0; n < NOUT; ++n) {
        const half_t* wr = Ws + n*1024 + lane*16;
        half8 w0 = *(const half8*)wr;
        half8 w1 = *(const half8*)(wr + 8);
        float s = 0.f;
        #pragma unroll
        for (int i = 0; i < 8; ++i) s += xa[i]*(float)w0[i] + xa[8+i]*(float)w1[i];
        #pragma unroll
        for (int off = 32; off > 0; off >>= 1) s += __shfl_down(s, off, 64);
        if (lane == 0) Y[(size_t)m*NOUT + n] = s + bias[n];
    }
}

// ---------------- launcher ----------------
extern "C" void kernel_launch(void* const* d_in, const int* in_sizes, int n_in,
                              void* d_out, int out_size, void* d_ws, size_t ws_size,
                              hipStream_t stream)
{
    const int*   text    = (const int*)  d_in[0];
    const float* emb     = (const float*)d_in[1];
    const float* emfc_w  = (const float*)d_in[2];
    const float* emfc_b  = (const float*)d_in[3];
    const float* w_ih0   = (const float*)d_in[4];
    const float* w_hh0   = (const float*)d_in[5];
    const float* b_ih0   = (const float*)d_in[6];
    const float* b_hh0   = (const float*)d_in[7];
    const float* w_ih1   = (const float*)d_in[8];
    const float* w_hh1   = (const float*)d_in[9];
    const float* b_ih1   = (const float*)d_in[10];
    const float* b_hh1   = (const float*)d_in[11];
    const float* fc_w    = (const float*)d_in[12];
    const float* fc_b    = (const float*)d_in[13];
    float* out = (float*)d_out;

    char* ws = (char*)d_ws;
    int*    cnt    = (int*)   (ws + O_CNT);
    ull_t*  hb0    = (ull_t*) (ws + O_HB0);
    ull_t*  hb1    = (ull_t*) (ws + O_HB1);
    half_t* emfc16 = (half_t*)(ws + O_EMFC16);
    half_t* wih0   = (half_t*)(ws + O_WIH0);
    half_t* wih1   = (half_t*)(ws + O_WIH1);
    half_t* fc16   = (half_t*)(ws + O_FC16);
    half_t* pe     = (half_t*)(ws + O_PE);
    half_t* xp     = (half_t*)(ws + O_XP);
    half_t* out0   = (half_t*)(ws + O_OUT0);
    half_t* out1   = (half_t*)(ws + O_OUT1);

    // 1) zero counters + h buffers  (524544 bytes = 32784 uint4)
    zero_ws<<<129, 256, 0, stream>>>((uint4*)ws, 32784);

    // 2) weight conversions fp32->fp16
    cvt_f32f16<<<32,  256, 0, stream>>>(emfc_w, emfc16, 8192);
    cvt_f32f16<<<128, 256, 0, stream>>>(w_ih0,  wih0,  32768);
    cvt_f32f16<<<512, 256, 0, stream>>>(w_ih1,  wih1, 131072);
    cvt_f32f16<<<9,   256, 0, stream>>>(fc_w,   fc16,   2304);

    // 3) post_emb = gather(emb, text) @ emfc_w^T + emfc_b
    gemm_nt<true><<<dim3(M_TOT/128, EMB/128), 256, 0, stream>>>(
        nullptr, emb, text, emfc16, emfc_b, nullptr, pe, M_TOT, EMB, EMB);

    // 4) xp0 = post_emb @ w_ih0^T + (b_ih0 + b_hh0)
    gemm_nt<false><<<dim3(M_TOT/128, (2*HID)/128), 256, 0, stream>>>(
        pe, nullptr, nullptr, wih0, b_ih0, b_hh0, xp, M_TOT, 2*HID, EMB);

    // 5) layer0 recurrence (both directions)
    rnn_layer<<<32, 256, 0, stream>>>(xp, out0, w_hh0, hb0, cnt);

    // 6) xp1 = out0 @ w_ih1^T + (b_ih1 + b_hh1)
    gemm_nt<false><<<dim3(M_TOT/128, (2*HID)/128), 256, 0, stream>>>(
        out0, nullptr, nullptr, wih1, b_ih1, b_hh1, xp, M_TOT, 2*HID, 2*HID);

    // 7) layer1 recurrence
    rnn_layer<<<32, 256, 0, stream>>>(xp, out1, w_hh1, hb1, cnt + 32);

    // 8) out = out1 @ fc_w^T + fc_b
    fc_kernel<<<M_TOT/4, 256, 0, stream>>>(out1, fc16, fc_b, out);
}